// Round 10
// baseline (63.358 us; speedup 1.0000x reference)
//
#include <hip/hip_runtime.h>
#include <hip/hip_bf16.h>
#include <math.h>

#define N_SYS   64
#define N_ELEC  64
#define NTOT    (N_SYS * N_ELEC)   // 4096
#define DIM     256
#define HEADS   8
#define LN_EPS  1e-6f

typedef __attribute__((ext_vector_type(8))) short bf16x8;
typedef __attribute__((ext_vector_type(4))) short short4v;
typedef __attribute__((ext_vector_type(4))) float f32x4;

static __device__ __forceinline__ short f2bf(float f) {
    __hip_bfloat16 h = __float2bfloat16(f);
    return *reinterpret_cast<short*>(&h);
}

// ===========================================================================
// Single fused kernel (grid 544 x 256 thr, 3 blocks/CU guaranteed):
//   bid 0..31   : weight transpose tiles -> WoutT/WmlpT; atomicAdd(cnt_w)
//   bid 32..543 : phase 1 = fused qkv GEMM + attention for (s = pb&63,
//                 h = pb>>6), pb = bid-32 (r8 structure, reg-prefetched
//                 staging). Producers of system s all live on XCD s%8.
//                 After attn stores: threadfence + atomicAdd(cnt_sys[s]).
//   bid 32..287 : additionally run the tail (out-proj+res, LN1, MLP+silu+res,
//                 LN2) for 16 rows of system s2 chosen so the tail block is
//                 on XCD s2%8 (same L2 as its producers). Spins (tid 0) on
//                 cnt_w==32 and cnt_sys[s2]==8.
// Co-residency: LDS union 47.1 KB + __launch_bounds__(256,3) -> 3 blocks/CU
// -> 768 slots >= 544 blocks -> every block dispatches; spins cannot starve.
// Counters zeroed each call by hipMemsetAsync (ws is poisoned by harness).
// ===========================================================================
__global__ __launch_bounds__(256, 3) void fused_k(
    const float* __restrict__ h_one, const float* __restrict__ W_qkv,
    const float* __restrict__ Wout, const float* __restrict__ Wmlp,
    const float* __restrict__ b_mlp,
    const float* __restrict__ ln1_s, const float* __restrict__ ln1_b,
    const float* __restrict__ ln2_s, const float* __restrict__ ln2_b,
    float* __restrict__ out,
    short* __restrict__ attn, short* __restrict__ WoutT,
    short* __restrict__ WmlpT, unsigned* __restrict__ cnt)  // cnt[0..63]=sys, cnt[64]=w
{
    const int tid = threadIdx.x;
    const int bid = blockIdx.x;

    __shared__ union {
        struct {
            short Ha[64][72];
            short Bs[96][72];
            short Qs[64][40];
            short Ks[64][40];
            short Vt[32][72];
            short Pm[64][72];
        } p1;                       // 47104 B
        struct {
            short Abf[16][264];
            float H1[16][260];
            short L1[16][264];
        } p2;                       // 33536 B
    } sm;

    const int lane = tid & 63;
    const int w = tid >> 6;
    const int l15 = lane & 15;
    const int l4 = lane >> 4;

    if (bid < 32) {
        // ---- weight transpose tiles (64x64)
        const int b2 = bid;
        const float* src = (b2 < 16) ? Wout : Wmlp;
        short* dst = (b2 < 16) ? WoutT : WmlpT;
        const int tile = b2 & 15;
        const int tk = (tile >> 2) * 64, tn = (tile & 3) * 64;
#pragma unroll
        for (int p = 0; p < 4; ++p) {
            int idx = p * 256 + tid;
            int kk = idx >> 4, n4 = (idx & 15) * 4;
            float4 v = *(const float4*)&src[(size_t)(tk + kk) * 256 + tn + n4];
            dst[(size_t)(tn + n4 + 0) * 256 + tk + kk] = f2bf(v.x);
            dst[(size_t)(tn + n4 + 1) * 256 + tk + kk] = f2bf(v.y);
            dst[(size_t)(tn + n4 + 2) * 256 + tk + kk] = f2bf(v.z);
            dst[(size_t)(tn + n4 + 3) * 256 + tk + kk] = f2bf(v.w);
        }
        __syncthreads();            // all stores issued & drained
        if (tid == 0) { __threadfence(); atomicAdd(&cnt[64], 1u); }
        return;
    }

    // ======================= phase 1 (r8 body) =============================
    const int pb = bid - 32;           // 0..511
    const int s = pb & 63;             // XCD-colocating map (bid%8 == s%8)
    const int h = pb >> 6;

    {
        auto& P = sm.p1;
        const float* Abase = h_one + (size_t)s * 64 * 256;
        const int rA = tid >> 3;          // A row (and row+32)
        const int cA8 = (tid & 7) * 8;    // A k-chunk
        const int bkk = tid >> 2;         // B: k row within step
        const int btt = tid & 3;          // B: float4 chunk phase

        float4 ra[2][4];
        float4 rb[2][6];

#define K1_LOAD(buf, kbase)                                                        \
        do {                                                                       \
            const float* ap0 = &Abase[(size_t)rA * 256 + (kbase) + cA8];           \
            const float* ap1 = &Abase[(size_t)(rA + 32) * 256 + (kbase) + cA8];    \
            ra[buf][0] = *(const float4*)ap0;                                      \
            ra[buf][1] = *(const float4*)(ap0 + 4);                                \
            ra[buf][2] = *(const float4*)ap1;                                      \
            ra[buf][3] = *(const float4*)(ap1 + 4);                                \
            _Pragma("unroll")                                                      \
            for (int q = 0; q < 6; ++q) {                                          \
                int c = btt + q * 4;                                               \
                int g = c >> 3;                                                    \
                int c4 = (c & 7) * 4;                                              \
                rb[buf][q] = *(const float4*)&W_qkv[(size_t)((kbase) + bkk) * 768  \
                                                    + g * 256 + h * 32 + c4];      \
            }                                                                      \
        } while (0)

        f32x4 acc[6] = {};
        K1_LOAD(0, 0);

#pragma unroll
        for (int kk = 0; kk < 4; ++kk) {
            const int k0 = kk * 64;
            const int cur = kk & 1;
            const int nxt = cur ^ 1;

            if (kk) __syncthreads();
            {
                bf16x8 o;
                o[0] = f2bf(ra[cur][0].x); o[1] = f2bf(ra[cur][0].y);
                o[2] = f2bf(ra[cur][0].z); o[3] = f2bf(ra[cur][0].w);
                o[4] = f2bf(ra[cur][1].x); o[5] = f2bf(ra[cur][1].y);
                o[6] = f2bf(ra[cur][1].z); o[7] = f2bf(ra[cur][1].w);
                *(bf16x8*)&P.Ha[rA][cA8] = o;
                o[0] = f2bf(ra[cur][2].x); o[1] = f2bf(ra[cur][2].y);
                o[2] = f2bf(ra[cur][2].z); o[3] = f2bf(ra[cur][2].w);
                o[4] = f2bf(ra[cur][3].x); o[5] = f2bf(ra[cur][3].y);
                o[6] = f2bf(ra[cur][3].z); o[7] = f2bf(ra[cur][3].w);
                *(bf16x8*)&P.Ha[rA + 32][cA8] = o;
            }
#pragma unroll
            for (int q = 0; q < 6; ++q) {
                int c = btt + q * 4;
                int g = c >> 3;
                int c4 = (c & 7) * 4;
                P.Bs[g * 32 + c4 + 0][bkk] = f2bf(rb[cur][q].x);
                P.Bs[g * 32 + c4 + 1][bkk] = f2bf(rb[cur][q].y);
                P.Bs[g * 32 + c4 + 2][bkk] = f2bf(rb[cur][q].z);
                P.Bs[g * 32 + c4 + 3][bkk] = f2bf(rb[cur][q].w);
            }
            if (kk < 3) K1_LOAD(nxt, k0 + 64);
            __syncthreads();

#pragma unroll
            for (int ki = 0; ki < 2; ++ki) {
                bf16x8 af = *(const bf16x8*)&P.Ha[w * 16 + l15][ki * 32 + l4 * 8];
#pragma unroll
                for (int nf = 0; nf < 6; ++nf) {
                    bf16x8 bfv = *(const bf16x8*)&P.Bs[nf * 16 + l15][ki * 32 + l4 * 8];
                    acc[nf] = __builtin_amdgcn_mfma_f32_16x16x32_bf16(af, bfv, acc[nf], 0, 0, 0);
                }
            }
        }
#undef K1_LOAD

        // scatter Q, K, V^T
#pragma unroll
        for (int nf = 0; nf < 6; ++nf) {
            int c = nf * 16 + l15;
#pragma unroll
            for (int j = 0; j < 4; ++j) {
                int row = w * 16 + l4 * 4 + j;
                short v = f2bf(acc[nf][j]);
                if (c < 32)       P.Qs[row][c] = v;
                else if (c < 64)  P.Ks[row][c - 32] = v;
                else              P.Vt[c - 64][row] = v;
            }
        }
        __syncthreads();

        // S^T = K @ Q^T, in-wave column softmax
        const float scale = 0.17677669529663687f;  // 1/sqrt(32)
        f32x4 sacc[4] = {};
        {
            bf16x8 ak = *(const bf16x8*)&P.Ks[w * 16 + l15][l4 * 8];
#pragma unroll
            for (int nf = 0; nf < 4; ++nf) {
                bf16x8 bq = *(const bf16x8*)&P.Qs[nf * 16 + l15][l4 * 8];
                sacc[nf] = __builtin_amdgcn_mfma_f32_16x16x32_bf16(ak, bq, sacc[nf], 0, 0, 0);
            }
        }
#pragma unroll
        for (int nf = 0; nf < 4; ++nf) sacc[nf] *= scale;
#pragma unroll
        for (int jj = 0; jj < 4; ++jj) {
            float mx = fmaxf(fmaxf(sacc[0][jj], sacc[1][jj]),
                             fmaxf(sacc[2][jj], sacc[3][jj]));
            mx = fmaxf(mx, __shfl_xor(mx, 1, 64));
            mx = fmaxf(mx, __shfl_xor(mx, 2, 64));
            mx = fmaxf(mx, __shfl_xor(mx, 4, 64));
            mx = fmaxf(mx, __shfl_xor(mx, 8, 64));
            float e0 = __expf(sacc[0][jj] - mx);
            float e1 = __expf(sacc[1][jj] - mx);
            float e2 = __expf(sacc[2][jj] - mx);
            float e3 = __expf(sacc[3][jj] - mx);
            float ss = e0 + e1 + e2 + e3;
            ss += __shfl_xor(ss, 1, 64);
            ss += __shfl_xor(ss, 2, 64);
            ss += __shfl_xor(ss, 4, 64);
            ss += __shfl_xor(ss, 8, 64);
            float inv = 1.0f / ss;
            sacc[0][jj] = e0 * inv; sacc[1][jj] = e1 * inv;
            sacc[2][jj] = e2 * inv; sacc[3][jj] = e3 * inv;
        }
#pragma unroll
        for (int nf = 0; nf < 4; ++nf) {
            short4v pq;
            pq[0] = f2bf(sacc[nf][0]); pq[1] = f2bf(sacc[nf][1]);
            pq[2] = f2bf(sacc[nf][2]); pq[3] = f2bf(sacc[nf][3]);
            *(short4v*)&P.Pm[nf * 16 + l15][w * 16 + l4 * 4] = pq;
        }
        __syncthreads();

        // attn = P @ V
        f32x4 pv[2] = {};
#pragma unroll
        for (int ki = 0; ki < 2; ++ki) {
            bf16x8 ap = *(const bf16x8*)&P.Pm[w * 16 + l15][ki * 32 + l4 * 8];
#pragma unroll
            for (int nf = 0; nf < 2; ++nf) {
                bf16x8 bv = *(const bf16x8*)&P.Vt[nf * 16 + l15][ki * 32 + l4 * 8];
                pv[nf] = __builtin_amdgcn_mfma_f32_16x16x32_bf16(ap, bv, pv[nf], 0, 0, 0);
            }
        }
#pragma unroll
        for (int nf = 0; nf < 2; ++nf)
#pragma unroll
            for (int j = 0; j < 4; ++j)
                attn[(size_t)(s * 64 + w * 16 + l4 * 4 + j) * 256 + h * 32 + nf * 16 + l15]
                    = f2bf(pv[nf][j]);
    }

    __syncthreads();                   // all attn stores drained (vmcnt=0)
    if (tid == 0) { __threadfence(); atomicAdd(&cnt[s], 1u); }

    if (pb >= 256) return;

    // ======================= tail (r5 phase-2 body) ========================
    // system s2 on the same XCD as this block: s2%8 == pb%8
    const int s2 = (pb & 7) + ((pb >> 5) << 3);
    const int rg = (pb >> 3) & 3;
    const int r0 = s2 * 64 + rg * 16;

    if (tid == 0) {
        int guard = 0;
        while (atomicAdd(&cnt[64], 0u) < 32u && guard < (1 << 22)) { __builtin_amdgcn_s_sleep(2); ++guard; }
        guard = 0;
        while (atomicAdd(&cnt[s2], 0u) < 8u && guard < (1 << 22)) { __builtin_amdgcn_s_sleep(2); ++guard; }
    }
    __syncthreads();                   // counters satisfied; p1 LDS reuse safe

    auto& T = sm.p2;

#pragma unroll
    for (int cc = 0; cc < 2; ++cc) {
        int c = tid * 2 + cc;
        int r = c >> 5, c8 = (c & 31) * 8;
        *(bf16x8*)&T.Abf[r][c8] = *(const bf16x8*)&attn[(size_t)(r0 + r) * 256 + c8];
    }
    __syncthreads();

    // GEMM1: wave w covers cols [w*64, +64)
    f32x4 acc[4] = {};
    for (int k0 = 0; k0 < 256; k0 += 32) {
        bf16x8 af = *(const bf16x8*)&T.Abf[l15][k0 + l4 * 8];
#pragma unroll
        for (int nf = 0; nf < 4; ++nf) {
            int n = w * 64 + nf * 16 + l15;
            bf16x8 bf = *(const bf16x8*)&WoutT[(size_t)n * 256 + k0 + l4 * 8];
            acc[nf] = __builtin_amdgcn_mfma_f32_16x16x32_bf16(af, bf, acc[nf], 0, 0, 0);
        }
    }
#pragma unroll
    for (int nf = 0; nf < 4; ++nf) {
        int col = w * 64 + nf * 16 + l15;
#pragma unroll
        for (int j = 0; j < 4; ++j) {
            int row = l4 * 4 + j;
            T.H1[row][col] = acc[nf][j] + h_one[(size_t)(r0 + row) * 256 + col];
        }
    }
    __syncthreads();

    // LN1: wave w -> rows w*4 .. w*4+3
    {
        float4 sc = *(const float4*)&ln1_s[lane * 4];
        float4 bi = *(const float4*)&ln1_b[lane * 4];
#pragma unroll
        for (int rr = 0; rr < 4; ++rr) {
            int row = w * 4 + rr;
            float4 v = *(const float4*)&T.H1[row][lane * 4];
            float su = v.x + v.y + v.z + v.w;
#pragma unroll
            for (int off = 32; off > 0; off >>= 1) su += __shfl_xor(su, off, 64);
            float mu = su * (1.0f / 256.0f);
            float dx = v.x - mu, dy = v.y - mu, dz = v.z - mu, dw = v.w - mu;
            float s2v = dx * dx + dy * dy + dz * dz + dw * dw;
#pragma unroll
            for (int off = 32; off > 0; off >>= 1) s2v += __shfl_xor(s2v, off, 64);
            float inv = rsqrtf(s2v * (1.0f / 256.0f) + LN_EPS);
            float4 o;
            o.x = dx * inv * sc.x + bi.x;
            o.y = dy * inv * sc.y + bi.y;
            o.z = dz * inv * sc.z + bi.z;
            o.w = dw * inv * sc.w + bi.w;
            *(float4*)&T.H1[row][lane * 4] = o;
            short4v ob;
            ob[0] = f2bf(o.x); ob[1] = f2bf(o.y); ob[2] = f2bf(o.z); ob[3] = f2bf(o.w);
            *(short4v*)&T.L1[row][lane * 4] = ob;
        }
    }
    __syncthreads();

    // GEMM2: h2 = H1 + silu(L1 @ WmlpT + b_mlp)
    f32x4 acc2[4] = {};
    for (int k0 = 0; k0 < 256; k0 += 32) {
        bf16x8 af = *(const bf16x8*)&T.L1[l15][k0 + l4 * 8];
#pragma unroll
        for (int nf = 0; nf < 4; ++nf) {
            int n = w * 64 + nf * 16 + l15;
            bf16x8 bf = *(const bf16x8*)&WmlpT[(size_t)n * 256 + k0 + l4 * 8];
            acc2[nf] = __builtin_amdgcn_mfma_f32_16x16x32_bf16(af, bf, acc2[nf], 0, 0, 0);
        }
    }
#pragma unroll
    for (int nf = 0; nf < 4; ++nf) {
        int col = w * 64 + nf * 16 + l15;
        float bm = b_mlp[col];
#pragma unroll
        for (int j = 0; j < 4; ++j) {
            int row = l4 * 4 + j;
            float v = acc2[nf][j] + bm;
            float sg = 1.0f / (1.0f + __expf(-v));
            T.H1[row][col] += v * sg;   // same-lane RMW
        }
    }
    __syncthreads();

    // LN2 -> out
    {
        float4 sc = *(const float4*)&ln2_s[lane * 4];
        float4 bi = *(const float4*)&ln2_b[lane * 4];
#pragma unroll
        for (int rr = 0; rr < 4; ++rr) {
            int row = w * 4 + rr;
            float4 v = *(const float4*)&T.H1[row][lane * 4];
            float su = v.x + v.y + v.z + v.w;
#pragma unroll
            for (int off = 32; off > 0; off >>= 1) su += __shfl_xor(su, off, 64);
            float mu = su * (1.0f / 256.0f);
            float dx = v.x - mu, dy = v.y - mu, dz = v.z - mu, dw = v.w - mu;
            float s2v = dx * dx + dy * dy + dz * dz + dw * dw;
#pragma unroll
            for (int off = 32; off > 0; off >>= 1) s2v += __shfl_xor(s2v, off, 64);
            float inv = rsqrtf(s2v * (1.0f / 256.0f) + LN_EPS);
            float4 o;
            o.x = dx * inv * sc.x + bi.x;
            o.y = dy * inv * sc.y + bi.y;
            o.z = dz * inv * sc.z + bi.z;
            o.w = dw * inv * sc.w + bi.w;
            *(float4*)&out[(size_t)(r0 + row) * 256 + lane * 4] = o;
        }
    }
}

// ---------------------------------------------------------------------------
extern "C" void kernel_launch(void* const* d_in, const int* in_sizes, int n_in,
                              void* d_out, int out_size, void* d_ws, size_t ws_size,
                              hipStream_t stream)
{
    const float* h_one = (const float*)d_in[0];
    const float* W_qkv = (const float*)d_in[1];
    const float* W_out = (const float*)d_in[2];
    const float* ln1_s = (const float*)d_in[3];
    const float* ln1_b = (const float*)d_in[4];
    const float* W_mlp = (const float*)d_in[5];
    const float* b_mlp = (const float*)d_in[6];
    const float* ln2_s = (const float*)d_in[7];
    const float* ln2_b = (const float*)d_in[8];
    float* out = (float*)d_out;

    char* ws = (char*)d_ws;
    short* attn_bf = (short*)ws;                            // 2 MB
    short* WoutT   = (short*)(ws + 2097152);                // 128 KB
    short* WmlpT   = WoutT + 256 * 256;                     // 128 KB
    unsigned* cnt  = (unsigned*)(ws + 2097152 + 262144);    // 65 u32

    hipMemsetAsync(cnt, 0, 65 * sizeof(unsigned), stream);
    fused_k<<<544, 256, 0, stream>>>(h_one, W_qkv, W_out, W_mlp, b_mlp,
                                     ln1_s, ln1_b, ln2_s, ln2_b, out,
                                     attn_bf, WoutT, WmlpT, cnt);
}

// Round 11
// 26.057 us; speedup vs baseline: 2.4315x; 2.4315x over previous
//
#include <hip/hip_runtime.h>
#include <hip/hip_bf16.h>
#include <math.h>

#define N_SYS   64
#define N_ELEC  64
#define NTOT    (N_SYS * N_ELEC)   // 4096
#define DIM     256
#define HEADS   8
#define LN_EPS  1e-6f

typedef __attribute__((ext_vector_type(8))) short bf16x8;
typedef __attribute__((ext_vector_type(4))) short short4v;
typedef __attribute__((ext_vector_type(4))) float f32x4;

static __device__ __forceinline__ short f2bf(float f) {
    __hip_bfloat16 h = __float2bfloat16(f);
    return *reinterpret_cast<short*>(&h);
}

// ---------------------------------------------------------------------------
// K1: blocks 0..511 : fused qkv-slice GEMM + attention for one (system, head).
//     s = b & 63, h = b >> 6 -> a system's 8 head-blocks share an XCD.
//     K-loop staging is register double-buffered (T14): next K-step's global
//     loads are issued before the current step's MFMAs, hiding load latency.
//     blocks 512..543: transpose-cast Wout/Wmlp f32 [K][N] -> bf16 [N][K].
// 256 threads = 4 waves.
// ---------------------------------------------------------------------------
__global__ __launch_bounds__(256) void k1_qkv_attn(
    const float* __restrict__ h_one, const float* __restrict__ W_qkv,
    const float* __restrict__ Wout, const float* __restrict__ Wmlp,
    short* __restrict__ attn, short* __restrict__ WoutT,
    short* __restrict__ WmlpT)
{
    const int tid = threadIdx.x;

    if (blockIdx.x >= 512) {
        // ---- weight transpose tiles (64x64)
        const int b2 = blockIdx.x - 512;
        const float* src = (b2 < 16) ? Wout : Wmlp;
        short* dst = (b2 < 16) ? WoutT : WmlpT;
        const int tile = b2 & 15;
        const int tk = (tile >> 2) * 64, tn = (tile & 3) * 64;
#pragma unroll
        for (int p = 0; p < 4; ++p) {
            int idx = p * 256 + tid;
            int kk = idx >> 4, n4 = (idx & 15) * 4;
            float4 v = *(const float4*)&src[(size_t)(tk + kk) * 256 + tn + n4];
            dst[(size_t)(tn + n4 + 0) * 256 + tk + kk] = f2bf(v.x);
            dst[(size_t)(tn + n4 + 1) * 256 + tk + kk] = f2bf(v.y);
            dst[(size_t)(tn + n4 + 2) * 256 + tk + kk] = f2bf(v.z);
            dst[(size_t)(tn + n4 + 3) * 256 + tk + kk] = f2bf(v.w);
        }
        return;
    }

    const int s = blockIdx.x & 63;     // XCD-colocating map
    const int h = blockIdx.x >> 6;

    __shared__ short Ha[64][72];    // A k-slice (bf16 of h_one rows)
    __shared__ short Bs[96][72];    // B^T k-slice: Bs[n][k] = W_qkv[k][col(n)]
    __shared__ short Qs[64][40];    // Q [i][d]
    __shared__ short Ks[64][40];    // K [j][d]
    __shared__ short Vt[32][72];    // V^T [d][j]
    __shared__ short Pm[64][72];    // P bf16 [i][j]

    const int lane = tid & 63;
    const int w = tid >> 6;
    const int l15 = lane & 15;
    const int l4 = lane >> 4;

    const float* Abase = h_one + (size_t)s * 64 * 256;
    const int rA = tid >> 3;          // A row (and row+32)
    const int cA8 = (tid & 7) * 8;    // A k-chunk
    const int bkk = tid >> 2;         // B: k row within step
    const int btt = tid & 3;          // B: float4 chunk phase

    // register staging buffers (double-buffered)
    float4 ra[2][4];
    float4 rb[2][6];

#define K1_LOAD(buf, kbase)                                                        \
    do {                                                                           \
        const float* ap0 = &Abase[(size_t)rA * 256 + (kbase) + cA8];               \
        const float* ap1 = &Abase[(size_t)(rA + 32) * 256 + (kbase) + cA8];        \
        ra[buf][0] = *(const float4*)ap0;                                          \
        ra[buf][1] = *(const float4*)(ap0 + 4);                                    \
        ra[buf][2] = *(const float4*)ap1;                                          \
        ra[buf][3] = *(const float4*)(ap1 + 4);                                    \
        _Pragma("unroll")                                                          \
        for (int q = 0; q < 6; ++q) {                                              \
            int c = btt + q * 4;                                                   \
            int g = c >> 3;                                                        \
            int c4 = (c & 7) * 4;                                                  \
            rb[buf][q] = *(const float4*)&W_qkv[(size_t)((kbase) + bkk) * 768      \
                                                + g * 256 + h * 32 + c4];          \
        }                                                                          \
    } while (0)

    f32x4 acc[6] = {};

    K1_LOAD(0, 0);

#pragma unroll
    for (int kk = 0; kk < 4; ++kk) {
        const int k0 = kk * 64;
        const int cur = kk & 1;
        const int nxt = cur ^ 1;

        if (kk) __syncthreads();      // prior-iteration LDS reads done
        // LDS writes from current register buffer
        {
            bf16x8 o;
            o[0] = f2bf(ra[cur][0].x); o[1] = f2bf(ra[cur][0].y);
            o[2] = f2bf(ra[cur][0].z); o[3] = f2bf(ra[cur][0].w);
            o[4] = f2bf(ra[cur][1].x); o[5] = f2bf(ra[cur][1].y);
            o[6] = f2bf(ra[cur][1].z); o[7] = f2bf(ra[cur][1].w);
            *(bf16x8*)&Ha[rA][cA8] = o;
            o[0] = f2bf(ra[cur][2].x); o[1] = f2bf(ra[cur][2].y);
            o[2] = f2bf(ra[cur][2].z); o[3] = f2bf(ra[cur][2].w);
            o[4] = f2bf(ra[cur][3].x); o[5] = f2bf(ra[cur][3].y);
            o[6] = f2bf(ra[cur][3].z); o[7] = f2bf(ra[cur][3].w);
            *(bf16x8*)&Ha[rA + 32][cA8] = o;
        }
#pragma unroll
        for (int q = 0; q < 6; ++q) {
            int c = btt + q * 4;
            int g = c >> 3;
            int c4 = (c & 7) * 4;
            Bs[g * 32 + c4 + 0][bkk] = f2bf(rb[cur][q].x);
            Bs[g * 32 + c4 + 1][bkk] = f2bf(rb[cur][q].y);
            Bs[g * 32 + c4 + 2][bkk] = f2bf(rb[cur][q].z);
            Bs[g * 32 + c4 + 3][bkk] = f2bf(rb[cur][q].w);
        }
        // issue next K-step's loads (latency hides under MFMA below)
        if (kk < 3) K1_LOAD(nxt, k0 + 64);
        __syncthreads();

#pragma unroll
        for (int ki = 0; ki < 2; ++ki) {
            bf16x8 af = *(const bf16x8*)&Ha[w * 16 + l15][ki * 32 + l4 * 8];
#pragma unroll
            for (int nf = 0; nf < 6; ++nf) {
                bf16x8 bfv = *(const bf16x8*)&Bs[nf * 16 + l15][ki * 32 + l4 * 8];
                acc[nf] = __builtin_amdgcn_mfma_f32_16x16x32_bf16(af, bfv, acc[nf], 0, 0, 0);
            }
        }
    }
#undef K1_LOAD

    // scatter Q, K, V^T (C-layout: row = w*16 + l4*4 + j, col = nf*16 + l15)
#pragma unroll
    for (int nf = 0; nf < 6; ++nf) {
        int c = nf * 16 + l15;
#pragma unroll
        for (int j = 0; j < 4; ++j) {
            int row = w * 16 + l4 * 4 + j;
            short v = f2bf(acc[nf][j]);
            if (c < 32)       Qs[row][c] = v;
            else if (c < 64)  Ks[row][c - 32] = v;
            else              Vt[c - 64][row] = v;
        }
    }
    __syncthreads();

    // S^T = K @ Q^T : wave w holds j-rows [w*16,+16), i-cols 0..63.
    // Column softmax (over i) fully in-wave: i spans {nf, l15}.
    const float scale = 0.17677669529663687f;  // 1/sqrt(32)
    f32x4 sacc[4] = {};
    {
        bf16x8 ak = *(const bf16x8*)&Ks[w * 16 + l15][l4 * 8];
#pragma unroll
        for (int nf = 0; nf < 4; ++nf) {
            bf16x8 bq = *(const bf16x8*)&Qs[nf * 16 + l15][l4 * 8];
            sacc[nf] = __builtin_amdgcn_mfma_f32_16x16x32_bf16(ak, bq, sacc[nf], 0, 0, 0);
        }
    }
#pragma unroll
    for (int nf = 0; nf < 4; ++nf) sacc[nf] *= scale;
#pragma unroll
    for (int jj = 0; jj < 4; ++jj) {
        float mx = fmaxf(fmaxf(sacc[0][jj], sacc[1][jj]),
                         fmaxf(sacc[2][jj], sacc[3][jj]));
        mx = fmaxf(mx, __shfl_xor(mx, 1, 64));
        mx = fmaxf(mx, __shfl_xor(mx, 2, 64));
        mx = fmaxf(mx, __shfl_xor(mx, 4, 64));
        mx = fmaxf(mx, __shfl_xor(mx, 8, 64));
        float e0 = __expf(sacc[0][jj] - mx);
        float e1 = __expf(sacc[1][jj] - mx);
        float e2 = __expf(sacc[2][jj] - mx);
        float e3 = __expf(sacc[3][jj] - mx);
        float ss = e0 + e1 + e2 + e3;
        ss += __shfl_xor(ss, 1, 64);
        ss += __shfl_xor(ss, 2, 64);
        ss += __shfl_xor(ss, 4, 64);
        ss += __shfl_xor(ss, 8, 64);
        float inv = 1.0f / ss;
        sacc[0][jj] = e0 * inv; sacc[1][jj] = e1 * inv;
        sacc[2][jj] = e2 * inv; sacc[3][jj] = e3 * inv;
    }
    // write P[i][j]: lane -> i = nf*16+l15, j-quad = w*16 + l4*4 (b64 stores)
#pragma unroll
    for (int nf = 0; nf < 4; ++nf) {
        short4v pq;
        pq[0] = f2bf(sacc[nf][0]); pq[1] = f2bf(sacc[nf][1]);
        pq[2] = f2bf(sacc[nf][2]); pq[3] = f2bf(sacc[nf][3]);
        *(short4v*)&Pm[nf * 16 + l15][w * 16 + l4 * 4] = pq;
    }
    __syncthreads();

    // attn = P @ V : wave w rows [w*16,+16), cols d 0..31
    f32x4 pv[2] = {};
#pragma unroll
    for (int ki = 0; ki < 2; ++ki) {
        bf16x8 ap = *(const bf16x8*)&Pm[w * 16 + l15][ki * 32 + l4 * 8];
#pragma unroll
        for (int nf = 0; nf < 2; ++nf) {
            bf16x8 bv = *(const bf16x8*)&Vt[nf * 16 + l15][ki * 32 + l4 * 8];
            pv[nf] = __builtin_amdgcn_mfma_f32_16x16x32_bf16(ap, bv, pv[nf], 0, 0, 0);
        }
    }
#pragma unroll
    for (int nf = 0; nf < 2; ++nf)
#pragma unroll
        for (int j = 0; j < 4; ++j)
            attn[(size_t)(s * 64 + w * 16 + l4 * 4 + j) * 256 + h * 32 + nf * 16 + l15]
                = f2bf(pv[nf][j]);
}

// ---------------------------------------------------------------------------
// K2: fused tail for 16 rows: out-proj+residual, LN1, MLP(silu)+residual, LN2.
// Grid 256 blocks x 512 threads (8 waves). Weight fragments prefetched one
// K-step ahead from global (L2-resident).
// ---------------------------------------------------------------------------
__global__ __launch_bounds__(512) void k2_tail(
    const short* __restrict__ attnbf, const short* __restrict__ WoutT,
    const short* __restrict__ WmlpT, const float* __restrict__ h_one,
    const float* __restrict__ b_mlp,
    const float* __restrict__ ln1_s, const float* __restrict__ ln1_b,
    const float* __restrict__ ln2_s, const float* __restrict__ ln2_b,
    float* __restrict__ out)
{
    const int r0 = blockIdx.x * 16;

    __shared__ short Abf[16][264];
    __shared__ float H1[16][260];
    __shared__ short L1[16][264];

    const int tid = threadIdx.x;
    const int lane = tid & 63;
    const int w = tid >> 6;           // 0..7
    const int l15 = lane & 15;
    const int l4 = lane >> 4;

    const size_t wrow0 = (size_t)(w * 32 + l15) * 256;       // nf=0 weight row
    const size_t wrow1 = (size_t)(w * 32 + 16 + l15) * 256;  // nf=1 weight row

    {
        int r = tid >> 5, c8 = (tid & 31) * 8;
        *(bf16x8*)&Abf[r][c8] = *(const bf16x8*)&attnbf[(size_t)(r0 + r) * 256 + c8];
    }
    __syncthreads();

    // GEMM1: wave w covers cols [w*32, +32), M=16, K=256 (B prefetched)
    f32x4 acc[2] = {};
    {
        bf16x8 bcur0 = *(const bf16x8*)&WoutT[wrow0 + l4 * 8];
        bf16x8 bcur1 = *(const bf16x8*)&WoutT[wrow1 + l4 * 8];
#pragma unroll
        for (int k0 = 0; k0 < 256; k0 += 32) {
            bf16x8 bnxt0, bnxt1;
            if (k0 < 224) {
                bnxt0 = *(const bf16x8*)&WoutT[wrow0 + k0 + 32 + l4 * 8];
                bnxt1 = *(const bf16x8*)&WoutT[wrow1 + k0 + 32 + l4 * 8];
            }
            bf16x8 af = *(const bf16x8*)&Abf[l15][k0 + l4 * 8];
            acc[0] = __builtin_amdgcn_mfma_f32_16x16x32_bf16(af, bcur0, acc[0], 0, 0, 0);
            acc[1] = __builtin_amdgcn_mfma_f32_16x16x32_bf16(af, bcur1, acc[1], 0, 0, 0);
            bcur0 = bnxt0; bcur1 = bnxt1;
        }
    }
#pragma unroll
    for (int nf = 0; nf < 2; ++nf) {
        int col = w * 32 + nf * 16 + l15;
#pragma unroll
        for (int j = 0; j < 4; ++j) {
            int row = l4 * 4 + j;
            H1[row][col] = acc[nf][j] + h_one[(size_t)(r0 + row) * 256 + col];
        }
    }
    __syncthreads();

    // LN1
    {
        float4 sc = *(const float4*)&ln1_s[lane * 4];
        float4 bi = *(const float4*)&ln1_b[lane * 4];
#pragma unroll
        for (int rr = 0; rr < 2; ++rr) {
            int row = w * 2 + rr;
            float4 v = *(const float4*)&H1[row][lane * 4];
            float su = v.x + v.y + v.z + v.w;
#pragma unroll
            for (int off = 32; off > 0; off >>= 1) su += __shfl_xor(su, off, 64);
            float mu = su * (1.0f / 256.0f);
            float dx = v.x - mu, dy = v.y - mu, dz = v.z - mu, dw = v.w - mu;
            float s2 = dx * dx + dy * dy + dz * dz + dw * dw;
#pragma unroll
            for (int off = 32; off > 0; off >>= 1) s2 += __shfl_xor(s2, off, 64);
            float inv = rsqrtf(s2 * (1.0f / 256.0f) + LN_EPS);
            float4 o;
            o.x = dx * inv * sc.x + bi.x;
            o.y = dy * inv * sc.y + bi.y;
            o.z = dz * inv * sc.z + bi.z;
            o.w = dw * inv * sc.w + bi.w;
            *(float4*)&H1[row][lane * 4] = o;
            short4v ob;
            ob[0] = f2bf(o.x); ob[1] = f2bf(o.y); ob[2] = f2bf(o.z); ob[3] = f2bf(o.w);
            *(short4v*)&L1[row][lane * 4] = ob;
        }
    }
    __syncthreads();

    // GEMM2: h2 = H1 + silu(L1 @ WmlpT + b_mlp) (B prefetched)
    f32x4 acc2[2] = {};
    {
        bf16x8 bcur0 = *(const bf16x8*)&WmlpT[wrow0 + l4 * 8];
        bf16x8 bcur1 = *(const bf16x8*)&WmlpT[wrow1 + l4 * 8];
#pragma unroll
        for (int k0 = 0; k0 < 256; k0 += 32) {
            bf16x8 bnxt0, bnxt1;
            if (k0 < 224) {
                bnxt0 = *(const bf16x8*)&WmlpT[wrow0 + k0 + 32 + l4 * 8];
                bnxt1 = *(const bf16x8*)&WmlpT[wrow1 + k0 + 32 + l4 * 8];
            }
            bf16x8 af = *(const bf16x8*)&L1[l15][k0 + l4 * 8];
            acc2[0] = __builtin_amdgcn_mfma_f32_16x16x32_bf16(af, bcur0, acc2[0], 0, 0, 0);
            acc2[1] = __builtin_amdgcn_mfma_f32_16x16x32_bf16(af, bcur1, acc2[1], 0, 0, 0);
            bcur0 = bnxt0; bcur1 = bnxt1;
        }
    }
#pragma unroll
    for (int nf = 0; nf < 2; ++nf) {
        int col = w * 32 + nf * 16 + l15;
        float bm = b_mlp[col];
#pragma unroll
        for (int j = 0; j < 4; ++j) {
            int row = l4 * 4 + j;
            float v = acc2[nf][j] + bm;
            float sg = 1.0f / (1.0f + __expf(-v));
            H1[row][col] = H1[row][col] + v * sg;   // same-lane RMW
        }
    }
    __syncthreads();

    // LN2 -> out
    {
        float4 sc = *(const float4*)&ln2_s[lane * 4];
        float4 bi = *(const float4*)&ln2_b[lane * 4];
#pragma unroll
        for (int rr = 0; rr < 2; ++rr) {
            int row = w * 2 + rr;
            float4 v = *(const float4*)&H1[row][lane * 4];
            float su = v.x + v.y + v.z + v.w;
#pragma unroll
            for (int off = 32; off > 0; off >>= 1) su += __shfl_xor(su, off, 64);
            float mu = su * (1.0f / 256.0f);
            float dx = v.x - mu, dy = v.y - mu, dz = v.z - mu, dw = v.w - mu;
            float s2 = dx * dx + dy * dy + dz * dz + dw * dw;
#pragma unroll
            for (int off = 32; off > 0; off >>= 1) s2 += __shfl_xor(s2, off, 64);
            float inv = rsqrtf(s2 * (1.0f / 256.0f) + LN_EPS);
            float4 o;
            o.x = dx * inv * sc.x + bi.x;
            o.y = dy * inv * sc.y + bi.y;
            o.z = dz * inv * sc.z + bi.z;
            o.w = dw * inv * sc.w + bi.w;
            *(float4*)&out[(size_t)(r0 + row) * 256 + lane * 4] = o;
        }
    }
}

// ---------------------------------------------------------------------------
extern "C" void kernel_launch(void* const* d_in, const int* in_sizes, int n_in,
                              void* d_out, int out_size, void* d_ws, size_t ws_size,
                              hipStream_t stream)
{
    const float* h_one = (const float*)d_in[0];
    const float* W_qkv = (const float*)d_in[1];
    const float* W_out = (const float*)d_in[2];
    const float* ln1_s = (const float*)d_in[3];
    const float* ln1_b = (const float*)d_in[4];
    const float* W_mlp = (const float*)d_in[5];
    const float* b_mlp = (const float*)d_in[6];
    const float* ln2_s = (const float*)d_in[7];
    const float* ln2_b = (const float*)d_in[8];
    float* out = (float*)d_out;

    char* ws = (char*)d_ws;
    short* attn_bf = (short*)ws;                 // 4096*256 bf16 = 2MB
    short* WoutT   = (short*)(ws + 2097152);     // 256*256 bf16 = 128KB
    short* WmlpT   = WoutT + 256 * 256;

    k1_qkv_attn<<<544, 256, 0, stream>>>(h_one, W_qkv, W_out, W_mlp,
                                         attn_bf, WoutT, WmlpT);
    k2_tail<<<256, 512, 0, stream>>>(attn_bf, WoutT, WmlpT, h_one, b_mlp,
                                     ln1_s, ln1_b, ln2_s, ln2_b, out);
}

// Round 12
// 25.583 us; speedup vs baseline: 2.4765x; 1.0185x over previous
//
#include <hip/hip_runtime.h>
#include <hip/hip_bf16.h>
#include <math.h>

#define N_SYS   64
#define N_ELEC  64
#define NTOT    (N_SYS * N_ELEC)   // 4096
#define DIM     256
#define HEADS   8
#define LN_EPS  1e-6f

typedef __attribute__((ext_vector_type(8))) short bf16x8;
typedef __attribute__((ext_vector_type(4))) short short4v;
typedef __attribute__((ext_vector_type(4))) float f32x4;

static __device__ __forceinline__ short f2bf(float f) {
    __hip_bfloat16 h = __float2bfloat16(f);
    return *reinterpret_cast<short*>(&h);
}

// ---------------------------------------------------------------------------
// K1: blocks 0..511 : fused qkv-slice GEMM + attention for one (system, head).
//     s = b & 63, h = b >> 6 -> a system's 8 head-blocks share an XCD (s%8).
//     K-loop staging is register double-buffered (T14): next K-step's global
//     loads are issued before the current step's MFMAs, hiding load latency.
//     blocks 512..543: transpose-cast Wout/Wmlp f32 [K][N] -> bf16 [N][K].
// 256 threads = 4 waves.
// ---------------------------------------------------------------------------
__global__ __launch_bounds__(256) void k1_qkv_attn(
    const float* __restrict__ h_one, const float* __restrict__ W_qkv,
    const float* __restrict__ Wout, const float* __restrict__ Wmlp,
    short* __restrict__ attn, short* __restrict__ WoutT,
    short* __restrict__ WmlpT)
{
    const int tid = threadIdx.x;

    if (blockIdx.x >= 512) {
        // ---- weight transpose tiles (64x64)
        const int b2 = blockIdx.x - 512;
        const float* src = (b2 < 16) ? Wout : Wmlp;
        short* dst = (b2 < 16) ? WoutT : WmlpT;
        const int tile = b2 & 15;
        const int tk = (tile >> 2) * 64, tn = (tile & 3) * 64;
#pragma unroll
        for (int p = 0; p < 4; ++p) {
            int idx = p * 256 + tid;
            int kk = idx >> 4, n4 = (idx & 15) * 4;
            float4 v = *(const float4*)&src[(size_t)(tk + kk) * 256 + tn + n4];
            dst[(size_t)(tn + n4 + 0) * 256 + tk + kk] = f2bf(v.x);
            dst[(size_t)(tn + n4 + 1) * 256 + tk + kk] = f2bf(v.y);
            dst[(size_t)(tn + n4 + 2) * 256 + tk + kk] = f2bf(v.z);
            dst[(size_t)(tn + n4 + 3) * 256 + tk + kk] = f2bf(v.w);
        }
        return;
    }

    const int s = blockIdx.x & 63;     // XCD-colocating map
    const int h = blockIdx.x >> 6;

    __shared__ short Ha[64][72];    // A k-slice (bf16 of h_one rows)
    __shared__ short Bs[96][72];    // B^T k-slice: Bs[n][k] = W_qkv[k][col(n)]
    __shared__ short Qs[64][40];    // Q [i][d]
    __shared__ short Ks[64][40];    // K [j][d]
    __shared__ short Vt[32][72];    // V^T [d][j]
    __shared__ short Pm[64][72];    // P bf16 [i][j]

    const int lane = tid & 63;
    const int w = tid >> 6;
    const int l15 = lane & 15;
    const int l4 = lane >> 4;

    const float* Abase = h_one + (size_t)s * 64 * 256;
    const int rA = tid >> 3;          // A row (and row+32)
    const int cA8 = (tid & 7) * 8;    // A k-chunk
    const int bkk = tid >> 2;         // B: k row within step
    const int btt = tid & 3;          // B: float4 chunk phase

    // register staging buffers (double-buffered)
    float4 ra[2][4];
    float4 rb[2][6];

#define K1_LOAD(buf, kbase)                                                        \
    do {                                                                           \
        const float* ap0 = &Abase[(size_t)rA * 256 + (kbase) + cA8];               \
        const float* ap1 = &Abase[(size_t)(rA + 32) * 256 + (kbase) + cA8];        \
        ra[buf][0] = *(const float4*)ap0;                                          \
        ra[buf][1] = *(const float4*)(ap0 + 4);                                    \
        ra[buf][2] = *(const float4*)ap1;                                          \
        ra[buf][3] = *(const float4*)(ap1 + 4);                                    \
        _Pragma("unroll")                                                          \
        for (int q = 0; q < 6; ++q) {                                              \
            int c = btt + q * 4;                                                   \
            int g = c >> 3;                                                        \
            int c4 = (c & 7) * 4;                                                  \
            rb[buf][q] = *(const float4*)&W_qkv[(size_t)((kbase) + bkk) * 768      \
                                                + g * 256 + h * 32 + c4];          \
        }                                                                          \
    } while (0)

    f32x4 acc[6] = {};

    K1_LOAD(0, 0);

#pragma unroll
    for (int kk = 0; kk < 4; ++kk) {
        const int k0 = kk * 64;
        const int cur = kk & 1;
        const int nxt = cur ^ 1;

        if (kk) __syncthreads();      // prior-iteration LDS reads done
        // LDS writes from current register buffer
        {
            bf16x8 o;
            o[0] = f2bf(ra[cur][0].x); o[1] = f2bf(ra[cur][0].y);
            o[2] = f2bf(ra[cur][0].z); o[3] = f2bf(ra[cur][0].w);
            o[4] = f2bf(ra[cur][1].x); o[5] = f2bf(ra[cur][1].y);
            o[6] = f2bf(ra[cur][1].z); o[7] = f2bf(ra[cur][1].w);
            *(bf16x8*)&Ha[rA][cA8] = o;
            o[0] = f2bf(ra[cur][2].x); o[1] = f2bf(ra[cur][2].y);
            o[2] = f2bf(ra[cur][2].z); o[3] = f2bf(ra[cur][2].w);
            o[4] = f2bf(ra[cur][3].x); o[5] = f2bf(ra[cur][3].y);
            o[6] = f2bf(ra[cur][3].z); o[7] = f2bf(ra[cur][3].w);
            *(bf16x8*)&Ha[rA + 32][cA8] = o;
        }
#pragma unroll
        for (int q = 0; q < 6; ++q) {
            int c = btt + q * 4;
            int g = c >> 3;
            int c4 = (c & 7) * 4;
            Bs[g * 32 + c4 + 0][bkk] = f2bf(rb[cur][q].x);
            Bs[g * 32 + c4 + 1][bkk] = f2bf(rb[cur][q].y);
            Bs[g * 32 + c4 + 2][bkk] = f2bf(rb[cur][q].z);
            Bs[g * 32 + c4 + 3][bkk] = f2bf(rb[cur][q].w);
        }
        // issue next K-step's loads (latency hides under MFMA below)
        if (kk < 3) K1_LOAD(nxt, k0 + 64);
        __syncthreads();

#pragma unroll
        for (int ki = 0; ki < 2; ++ki) {
            bf16x8 af = *(const bf16x8*)&Ha[w * 16 + l15][ki * 32 + l4 * 8];
#pragma unroll
            for (int nf = 0; nf < 6; ++nf) {
                bf16x8 bfv = *(const bf16x8*)&Bs[nf * 16 + l15][ki * 32 + l4 * 8];
                acc[nf] = __builtin_amdgcn_mfma_f32_16x16x32_bf16(af, bfv, acc[nf], 0, 0, 0);
            }
        }
    }
#undef K1_LOAD

    // scatter Q, K, V^T (C-layout: row = w*16 + l4*4 + j, col = nf*16 + l15)
#pragma unroll
    for (int nf = 0; nf < 6; ++nf) {
        int c = nf * 16 + l15;
#pragma unroll
        for (int j = 0; j < 4; ++j) {
            int row = w * 16 + l4 * 4 + j;
            short v = f2bf(acc[nf][j]);
            if (c < 32)       Qs[row][c] = v;
            else if (c < 64)  Ks[row][c - 32] = v;
            else              Vt[c - 64][row] = v;
        }
    }
    __syncthreads();

    // S^T = K @ Q^T : wave w holds j-rows [w*16,+16), i-cols 0..63.
    // Column softmax (over i) fully in-wave: i spans {nf, l15}.
    const float scale = 0.17677669529663687f;  // 1/sqrt(32)
    f32x4 sacc[4] = {};
    {
        bf16x8 ak = *(const bf16x8*)&Ks[w * 16 + l15][l4 * 8];
#pragma unroll
        for (int nf = 0; nf < 4; ++nf) {
            bf16x8 bq = *(const bf16x8*)&Qs[nf * 16 + l15][l4 * 8];
            sacc[nf] = __builtin_amdgcn_mfma_f32_16x16x32_bf16(ak, bq, sacc[nf], 0, 0, 0);
        }
    }
#pragma unroll
    for (int nf = 0; nf < 4; ++nf) sacc[nf] *= scale;
#pragma unroll
    for (int jj = 0; jj < 4; ++jj) {
        float mx = fmaxf(fmaxf(sacc[0][jj], sacc[1][jj]),
                         fmaxf(sacc[2][jj], sacc[3][jj]));
        mx = fmaxf(mx, __shfl_xor(mx, 1, 64));
        mx = fmaxf(mx, __shfl_xor(mx, 2, 64));
        mx = fmaxf(mx, __shfl_xor(mx, 4, 64));
        mx = fmaxf(mx, __shfl_xor(mx, 8, 64));
        float e0 = __expf(sacc[0][jj] - mx);
        float e1 = __expf(sacc[1][jj] - mx);
        float e2 = __expf(sacc[2][jj] - mx);
        float e3 = __expf(sacc[3][jj] - mx);
        float ss = e0 + e1 + e2 + e3;
        ss += __shfl_xor(ss, 1, 64);
        ss += __shfl_xor(ss, 2, 64);
        ss += __shfl_xor(ss, 4, 64);
        ss += __shfl_xor(ss, 8, 64);
        float inv = 1.0f / ss;
        sacc[0][jj] = e0 * inv; sacc[1][jj] = e1 * inv;
        sacc[2][jj] = e2 * inv; sacc[3][jj] = e3 * inv;
    }
    // write P[i][j]: lane -> i = nf*16+l15, j-quad = w*16 + l4*4 (b64 stores)
#pragma unroll
    for (int nf = 0; nf < 4; ++nf) {
        short4v pq;
        pq[0] = f2bf(sacc[nf][0]); pq[1] = f2bf(sacc[nf][1]);
        pq[2] = f2bf(sacc[nf][2]); pq[3] = f2bf(sacc[nf][3]);
        *(short4v*)&Pm[nf * 16 + l15][w * 16 + l4 * 4] = pq;
    }
    __syncthreads();

    // attn = P @ V : wave w rows [w*16,+16), cols d 0..31
    f32x4 pv[2] = {};
#pragma unroll
    for (int ki = 0; ki < 2; ++ki) {
        bf16x8 ap = *(const bf16x8*)&Pm[w * 16 + l15][ki * 32 + l4 * 8];
#pragma unroll
        for (int nf = 0; nf < 2; ++nf) {
            bf16x8 bv = *(const bf16x8*)&Vt[nf * 16 + l15][ki * 32 + l4 * 8];
            pv[nf] = __builtin_amdgcn_mfma_f32_16x16x32_bf16(ap, bv, pv[nf], 0, 0, 0);
        }
    }
#pragma unroll
    for (int nf = 0; nf < 2; ++nf)
#pragma unroll
        for (int j = 0; j < 4; ++j)
            attn[(size_t)(s * 64 + w * 16 + l4 * 4 + j) * 256 + h * 32 + nf * 16 + l15]
                = f2bf(pv[nf][j]);
}

// ---------------------------------------------------------------------------
// K2: fused tail for 16 rows: out-proj+residual, LN1, MLP(silu)+residual, LN2.
// Grid 256 blocks x 512 threads (8 waves). Weight fragments prefetched one
// K-step ahead from global (L2-resident).
// Block->system map is XCD-aligned with K1's producers: block b (XCD b%8)
// handles system s = (b&7) + 8*((b>>3)&7), row group g = b>>6... see below —
// so its attn rows + h_one slice are already in the local L2.
// ---------------------------------------------------------------------------
__global__ __launch_bounds__(512) void k2_tail(
    const short* __restrict__ attnbf, const short* __restrict__ WoutT,
    const short* __restrict__ WmlpT, const float* __restrict__ h_one,
    const float* __restrict__ b_mlp,
    const float* __restrict__ ln1_s, const float* __restrict__ ln1_b,
    const float* __restrict__ ln2_s, const float* __restrict__ ln2_b,
    float* __restrict__ out)
{
    // XCD-aligned remap: x = b&7 (XCD), y = b>>3; s = x + 8*(y&7); g = y>>3.
    // Bijective over (s in [0,64)) x (g in [0,4)); s%8 == b%8 == producer XCD.
    const int b = blockIdx.x;
    const int s = (b & 7) + 8 * ((b >> 3) & 7);
    const int g = b >> 6;
    const int r0 = s * 64 + g * 16;

    __shared__ short Abf[16][264];
    __shared__ float H1[16][260];
    __shared__ short L1[16][264];

    const int tid = threadIdx.x;
    const int lane = tid & 63;
    const int w = tid >> 6;           // 0..7
    const int l15 = lane & 15;
    const int l4 = lane >> 4;

    const size_t wrow0 = (size_t)(w * 32 + l15) * 256;       // nf=0 weight row
    const size_t wrow1 = (size_t)(w * 32 + 16 + l15) * 256;  // nf=1 weight row

    {
        int r = tid >> 5, c8 = (tid & 31) * 8;
        *(bf16x8*)&Abf[r][c8] = *(const bf16x8*)&attnbf[(size_t)(r0 + r) * 256 + c8];
    }
    __syncthreads();

    // GEMM1: wave w covers cols [w*32, +32), M=16, K=256 (B prefetched)
    f32x4 acc[2] = {};
    {
        bf16x8 bcur0 = *(const bf16x8*)&WoutT[wrow0 + l4 * 8];
        bf16x8 bcur1 = *(const bf16x8*)&WoutT[wrow1 + l4 * 8];
#pragma unroll
        for (int k0 = 0; k0 < 256; k0 += 32) {
            bf16x8 bnxt0, bnxt1;
            if (k0 < 224) {
                bnxt0 = *(const bf16x8*)&WoutT[wrow0 + k0 + 32 + l4 * 8];
                bnxt1 = *(const bf16x8*)&WoutT[wrow1 + k0 + 32 + l4 * 8];
            }
            bf16x8 af = *(const bf16x8*)&Abf[l15][k0 + l4 * 8];
            acc[0] = __builtin_amdgcn_mfma_f32_16x16x32_bf16(af, bcur0, acc[0], 0, 0, 0);
            acc[1] = __builtin_amdgcn_mfma_f32_16x16x32_bf16(af, bcur1, acc[1], 0, 0, 0);
            bcur0 = bnxt0; bcur1 = bnxt1;
        }
    }
#pragma unroll
    for (int nf = 0; nf < 2; ++nf) {
        int col = w * 32 + nf * 16 + l15;
#pragma unroll
        for (int j = 0; j < 4; ++j) {
            int row = l4 * 4 + j;
            H1[row][col] = acc[nf][j] + h_one[(size_t)(r0 + row) * 256 + col];
        }
    }
    __syncthreads();

    // LN1
    {
        float4 sc = *(const float4*)&ln1_s[lane * 4];
        float4 bi = *(const float4*)&ln1_b[lane * 4];
#pragma unroll
        for (int rr = 0; rr < 2; ++rr) {
            int row = w * 2 + rr;
            float4 v = *(const float4*)&H1[row][lane * 4];
            float su = v.x + v.y + v.z + v.w;
#pragma unroll
            for (int off = 32; off > 0; off >>= 1) su += __shfl_xor(su, off, 64);
            float mu = su * (1.0f / 256.0f);
            float dx = v.x - mu, dy = v.y - mu, dz = v.z - mu, dw = v.w - mu;
            float s2 = dx * dx + dy * dy + dz * dz + dw * dw;
#pragma unroll
            for (int off = 32; off > 0; off >>= 1) s2 += __shfl_xor(s2, off, 64);
            float inv = rsqrtf(s2 * (1.0f / 256.0f) + LN_EPS);
            float4 o;
            o.x = dx * inv * sc.x + bi.x;
            o.y = dy * inv * sc.y + bi.y;
            o.z = dz * inv * sc.z + bi.z;
            o.w = dw * inv * sc.w + bi.w;
            *(float4*)&H1[row][lane * 4] = o;
            short4v ob;
            ob[0] = f2bf(o.x); ob[1] = f2bf(o.y); ob[2] = f2bf(o.z); ob[3] = f2bf(o.w);
            *(short4v*)&L1[row][lane * 4] = ob;
        }
    }
    __syncthreads();

    // GEMM2: h2 = H1 + silu(L1 @ WmlpT + b_mlp) (B prefetched)
    f32x4 acc2[2] = {};
    {
        bf16x8 bcur0 = *(const bf16x8*)&WmlpT[wrow0 + l4 * 8];
        bf16x8 bcur1 = *(const bf16x8*)&WmlpT[wrow1 + l4 * 8];
#pragma unroll
        for (int k0 = 0; k0 < 256; k0 += 32) {
            bf16x8 bnxt0, bnxt1;
            if (k0 < 224) {
                bnxt0 = *(const bf16x8*)&WmlpT[wrow0 + k0 + 32 + l4 * 8];
                bnxt1 = *(const bf16x8*)&WmlpT[wrow1 + k0 + 32 + l4 * 8];
            }
            bf16x8 af = *(const bf16x8*)&L1[l15][k0 + l4 * 8];
            acc2[0] = __builtin_amdgcn_mfma_f32_16x16x32_bf16(af, bcur0, acc2[0], 0, 0, 0);
            acc2[1] = __builtin_amdgcn_mfma_f32_16x16x32_bf16(af, bcur1, acc2[1], 0, 0, 0);
            bcur0 = bnxt0; bcur1 = bnxt1;
        }
    }
#pragma unroll
    for (int nf = 0; nf < 2; ++nf) {
        int col = w * 32 + nf * 16 + l15;
        float bm = b_mlp[col];
#pragma unroll
        for (int j = 0; j < 4; ++j) {
            int row = l4 * 4 + j;
            float v = acc2[nf][j] + bm;
            float sg = 1.0f / (1.0f + __expf(-v));
            H1[row][col] = H1[row][col] + v * sg;   // same-lane RMW
        }
    }
    __syncthreads();

    // LN2 -> out
    {
        float4 sc = *(const float4*)&ln2_s[lane * 4];
        float4 bi = *(const float4*)&ln2_b[lane * 4];
#pragma unroll
        for (int rr = 0; rr < 2; ++rr) {
            int row = w * 2 + rr;
            float4 v = *(const float4*)&H1[row][lane * 4];
            float su = v.x + v.y + v.z + v.w;
#pragma unroll
            for (int off = 32; off > 0; off >>= 1) su += __shfl_xor(su, off, 64);
            float mu = su * (1.0f / 256.0f);
            float dx = v.x - mu, dy = v.y - mu, dz = v.z - mu, dw = v.w - mu;
            float s2 = dx * dx + dy * dy + dz * dz + dw * dw;
#pragma unroll
            for (int off = 32; off > 0; off >>= 1) s2 += __shfl_xor(s2, off, 64);
            float inv = rsqrtf(s2 * (1.0f / 256.0f) + LN_EPS);
            float4 o;
            o.x = dx * inv * sc.x + bi.x;
            o.y = dy * inv * sc.y + bi.y;
            o.z = dz * inv * sc.z + bi.z;
            o.w = dw * inv * sc.w + bi.w;
            *(float4*)&out[(size_t)(r0 + row) * 256 + lane * 4] = o;
        }
    }
}

// ---------------------------------------------------------------------------
extern "C" void kernel_launch(void* const* d_in, const int* in_sizes, int n_in,
                              void* d_out, int out_size, void* d_ws, size_t ws_size,
                              hipStream_t stream)
{
    const float* h_one = (const float*)d_in[0];
    const float* W_qkv = (const float*)d_in[1];
    const float* W_out = (const float*)d_in[2];
    const float* ln1_s = (const float*)d_in[3];
    const float* ln1_b = (const float*)d_in[4];
    const float* W_mlp = (const float*)d_in[5];
    const float* b_mlp = (const float*)d_in[6];
    const float* ln2_s = (const float*)d_in[7];
    const float* ln2_b = (const float*)d_in[8];
    float* out = (float*)d_out;

    char* ws = (char*)d_ws;
    short* attn_bf = (short*)ws;                 // 4096*256 bf16 = 2MB
    short* WoutT   = (short*)(ws + 2097152);     // 256*256 bf16 = 128KB
    short* WmlpT   = WoutT + 256 * 256;

    k1_qkv_attn<<<544, 256, 0, stream>>>(h_one, W_qkv, W_out, W_mlp,
                                         attn_bf, WoutT, WmlpT);
    k2_tail<<<256, 512, 0, stream>>>(attn_bf, WoutT, WmlpT, h_one, b_mlp,
                                     ln1_s, ln1_b, ln2_s, ln2_b, out);
}